// Round 1
// baseline (761.549 us; speedup 1.0000x reference)
//
#include <hip/hip_runtime.h>

// Problem constants (match reference)
#define NN 100000
#define TT 128
#define EE 1600000
#define KK 9
#define PADK 4
#define CH 1024
#define NB ((NN + CH - 1) / CH)   // 98 scan chunks
#define NSPLIT 8                  // n-splits for output matmul

// ---------- CSR build ----------

__global__ void hist_kernel(const int* __restrict__ ei, int* __restrict__ deg) {
    int e = blockIdx.x * blockDim.x + threadIdx.x;
    if (e < EE) atomicAdd(&deg[ei[EE + e]], 1);   // dst row of edge_index
}

__global__ void partial_kernel(const int* __restrict__ deg, int* __restrict__ part) {
    __shared__ int sm[256];
    int base = blockIdx.x * CH;
    int s = 0;
    for (int j = threadIdx.x; j < CH; j += 256) {
        int i = base + j;
        if (i < NN) s += deg[i];
    }
    sm[threadIdx.x] = s;
    __syncthreads();
    for (int off = 128; off > 0; off >>= 1) {
        if (threadIdx.x < off) sm[threadIdx.x] += sm[threadIdx.x + off];
        __syncthreads();
    }
    if (threadIdx.x == 0) part[blockIdx.x] = sm[0];
}

__global__ void scanpart_kernel(int* __restrict__ part, int* __restrict__ offsets) {
    __shared__ int sm[128];
    int tid = threadIdx.x;
    sm[tid] = (tid < NB) ? part[tid] : 0;
    __syncthreads();
    for (int off = 1; off < 128; off <<= 1) {
        int v = (tid >= off) ? sm[tid - off] : 0;
        __syncthreads();
        sm[tid] += v;
        __syncthreads();
    }
    if (tid < NB) part[tid] = (tid == 0) ? 0 : sm[tid - 1];  // exclusive block sums
    if (tid == 0) offsets[NN] = EE;
}

__global__ void scanchunk_kernel(const int* __restrict__ deg, const int* __restrict__ part,
                                 int* __restrict__ offsets, float* __restrict__ inv_cnt) {
    __shared__ int sm[256];
    int tid = threadIdx.x;
    int base = blockIdx.x * CH + tid * 4;
    int d0 = 0, d1 = 0, d2 = 0, d3 = 0;
    if (base + 0 < NN) d0 = deg[base + 0];
    if (base + 1 < NN) d1 = deg[base + 1];
    if (base + 2 < NN) d2 = deg[base + 2];
    if (base + 3 < NN) d3 = deg[base + 3];
    sm[tid] = d0 + d1 + d2 + d3;
    __syncthreads();
    for (int off = 1; off < 256; off <<= 1) {
        int v = (tid >= off) ? sm[tid - off] : 0;
        __syncthreads();
        sm[tid] += v;
        __syncthreads();
    }
    int carry = part[blockIdx.x] + ((tid == 0) ? 0 : sm[tid - 1]);
    int p0 = carry;
    int p1 = p0 + d0;
    int p2 = p1 + d1;
    int p3 = p2 + d2;
    if (base + 0 < NN) { offsets[base + 0] = p0; inv_cnt[base + 0] = 1.0f / (1.0f + (float)d0); }
    if (base + 1 < NN) { offsets[base + 1] = p1; inv_cnt[base + 1] = 1.0f / (1.0f + (float)d1); }
    if (base + 2 < NN) { offsets[base + 2] = p2; inv_cnt[base + 2] = 1.0f / (1.0f + (float)d2); }
    if (base + 3 < NN) { offsets[base + 3] = p3; inv_cnt[base + 3] = 1.0f / (1.0f + (float)d3); }
}

__global__ void place_kernel(const int* __restrict__ ei, int* __restrict__ cursor,
                             int* __restrict__ col) {
    int e = blockIdx.x * blockDim.x + threadIdx.x;
    if (e < EE) {
        int s = ei[e];            // src
        int d = ei[EE + e];       // dst
        int p = atomicAdd(&cursor[d], 1);
        col[p] = s;
    }
}

// ---------- per-layer compute ----------

// h[n,t] = b + sum_k relu_scale(xin[n, t+k-4]) * w[k]; 2 nodes per 256-thread block.
__global__ void conv_kernel(const float* __restrict__ xin, const float* __restrict__ inv_cnt,
                            const float* __restrict__ w9, const float* __restrict__ bptr,
                            float* __restrict__ h, int scaled) {
    __shared__ float row[2][TT + 2 * PADK];
    int tid = threadIdx.x;
    int r = tid >> 7;
    int t = tid & 127;
    int node = blockIdx.x * 2 + r;
    float v = xin[node * TT + t];
    if (scaled) {
        v *= inv_cnt[node];
        v = fmaxf(v, 0.0f);
    }
    row[r][PADK + t] = v;
    if (t < PADK) row[r][t] = 0.0f;
    if (t >= TT - PADK) row[r][t + 2 * PADK] = 0.0f;
    __syncthreads();
    float acc = bptr[0];
#pragma unroll
    for (int k = 0; k < KK; k++) acc += row[r][t + k] * w9[k];
    h[node * TT + t] = acc;
}

// s[n,t] = h[n,t] (self loop) + sum_{j in CSR row n} h[col[j], t]
__global__ void gather_kernel(const float* __restrict__ h, const int* __restrict__ offsets,
                              const int* __restrict__ col, float* __restrict__ out) {
    int node = blockIdx.x;
    int t = threadIdx.x;
    float acc = h[node * TT + t];
    int lo = offsets[node], hi = offsets[node + 1];
    int j = lo;
    for (; j + 1 < hi; j += 2) {
        int n0 = col[j];
        int n1 = col[j + 1];
        float v0 = h[n0 * TT + t];
        float v1 = h[n1 * TT + t];
        acc += v0;
        acc += v1;
    }
    if (j < hi) acc += h[col[j] * TT + t];
    out[node * TT + t] = acc;
}

// out[t,c] = b[c] + sum_n relu(s[t*NN+n] * inv_cnt[(t*NN+n)>>7]) * Wout[c*NN+n]
__global__ void out_kernel(const float* __restrict__ s3, const float* __restrict__ inv_cnt,
                           const float* __restrict__ Wout, const float* __restrict__ bout,
                           float* __restrict__ out) {
    int t = blockIdx.x;
    int sp = blockIdx.y;
    int tid = threadIdx.x;
    const int per = NN / NSPLIT;   // 12500
    int lo = sp * per;
    int hi = lo + per;
    float a0 = 0.0f, a1 = 0.0f, a2 = 0.0f;
    for (int n = lo + tid; n < hi; n += 256) {
        int f = t * NN + n;
        float v = s3[f] * inv_cnt[f >> 7];
        v = fmaxf(v, 0.0f);
        a0 += v * Wout[n];
        a1 += v * Wout[NN + n];
        a2 += v * Wout[2 * NN + n];
    }
    // wave reduce (wave = 64)
    for (int o = 32; o > 0; o >>= 1) {
        a0 += __shfl_down(a0, o);
        a1 += __shfl_down(a1, o);
        a2 += __shfl_down(a2, o);
    }
    __shared__ float red[4][3];
    int wave = tid >> 6;
    if ((tid & 63) == 0) {
        red[wave][0] = a0;
        red[wave][1] = a1;
        red[wave][2] = a2;
    }
    __syncthreads();
    if (tid == 0) {
        float r0 = red[0][0] + red[1][0] + red[2][0] + red[3][0];
        float r1 = red[0][1] + red[1][1] + red[2][1] + red[3][1];
        float r2 = red[0][2] + red[1][2] + red[2][2] + red[3][2];
        if (sp == 0) {
            r0 += bout[0];
            r1 += bout[1];
            r2 += bout[2];
        }
        atomicAdd(&out[t * 3 + 0], r0);
        atomicAdd(&out[t * 3 + 1], r1);
        atomicAdd(&out[t * 3 + 2], r2);
    }
}

extern "C" void kernel_launch(void* const* d_in, const int* in_sizes, int n_in,
                              void* d_out, int out_size, void* d_ws, size_t ws_size,
                              hipStream_t stream) {
    const float* x    = (const float*)d_in[0];   // [N,T]
    const int*   ei   = (const int*)d_in[1];     // [2,E]
    const float* cw   = (const float*)d_in[2];   // [L,1,1,K]
    const float* cb   = (const float*)d_in[3];   // [L,1]
    const float* Wout = (const float*)d_in[4];   // [3,N]
    const float* bout = (const float*)d_in[5];   // [3]
    float* out = (float*)d_out;                  // [T,3]

    char* ws = (char*)d_ws;
    size_t off = 0;
    auto alloc = [&](size_t bytes) -> void* {
        void* p = ws + off;
        off += (bytes + 255) & ~(size_t)255;
        return p;
    };
    float* h       = (float*)alloc((size_t)NN * TT * 4);
    float* B       = (float*)alloc((size_t)NN * TT * 4);
    int*   deg     = (int*)alloc((size_t)NN * 4);
    int*   offsets = (int*)alloc((size_t)(NN + 1) * 4);
    int*   cursor  = (int*)alloc((size_t)NN * 4);
    int*   col     = (int*)alloc((size_t)EE * 4);
    float* inv_cnt = (float*)alloc((size_t)NN * 4);
    int*   part    = (int*)alloc((size_t)NB * 4);

    // CSR build (per call — inputs are restored before every launch)
    hipMemsetAsync(deg, 0, (size_t)NN * 4, stream);
    hist_kernel<<<(EE + 255) / 256, 256, 0, stream>>>(ei, deg);
    partial_kernel<<<NB, 256, 0, stream>>>(deg, part);
    scanpart_kernel<<<1, 128, 0, stream>>>(part, offsets);
    scanchunk_kernel<<<NB, 256, 0, stream>>>(deg, part, offsets, inv_cnt);
    hipMemcpyAsync(cursor, offsets, (size_t)NN * 4, hipMemcpyDeviceToDevice, stream);
    place_kernel<<<(EE + 255) / 256, 256, 0, stream>>>(ei, cursor, col);

    // 3 layers: conv (with fused relu/scale of previous aggregate) then gather
    const float* xin = x;
    for (int l = 0; l < 3; l++) {
        conv_kernel<<<NN / 2, 256, 0, stream>>>(xin, inv_cnt, cw + l * KK, cb + l, h, l > 0 ? 1 : 0);
        gather_kernel<<<NN, 128, 0, stream>>>(h, offsets, col, B);
        xin = B;
    }

    // output head: relu/scale fused into load; flat reinterpret [T,N]
    hipMemsetAsync(out, 0, (size_t)TT * 3 * 4, stream);
    out_kernel<<<dim3(TT, NSPLIT), 256, 0, stream>>>(B, inv_cnt, Wout, bout, out);
}

// Round 2
// 505.921 us; speedup vs baseline: 1.5053x; 1.5053x over previous
//
#include <hip/hip_runtime.h>

// Problem constants (match reference)
#define NN 100000
#define TT 128
#define EE 1600000
#define KK 9
#define PADK 4
#define CH 1024
#define NB ((NN + CH - 1) / CH)   // 98 scan chunks
#define NSPLIT 8                  // n-splits for output matmul

typedef _Float16 f16;
typedef __attribute__((ext_vector_type(2))) _Float16 f16x2;
typedef __attribute__((ext_vector_type(4))) _Float16 f16x4;

// ---------- CSR build ----------

__global__ void hist_kernel(const int* __restrict__ ei, int* __restrict__ deg) {
    int e = blockIdx.x * blockDim.x + threadIdx.x;
    if (e < EE) atomicAdd(&deg[ei[EE + e]], 1);   // dst row of edge_index
}

__global__ void partial_kernel(const int* __restrict__ deg, int* __restrict__ part) {
    __shared__ int sm[256];
    int base = blockIdx.x * CH;
    int s = 0;
    for (int j = threadIdx.x; j < CH; j += 256) {
        int i = base + j;
        if (i < NN) s += deg[i];
    }
    sm[threadIdx.x] = s;
    __syncthreads();
    for (int off = 128; off > 0; off >>= 1) {
        if (threadIdx.x < off) sm[threadIdx.x] += sm[threadIdx.x + off];
        __syncthreads();
    }
    if (threadIdx.x == 0) part[blockIdx.x] = sm[0];
}

__global__ void scanpart_kernel(int* __restrict__ part, int* __restrict__ offsets) {
    __shared__ int sm[128];
    int tid = threadIdx.x;
    sm[tid] = (tid < NB) ? part[tid] : 0;
    __syncthreads();
    for (int off = 1; off < 128; off <<= 1) {
        int v = (tid >= off) ? sm[tid - off] : 0;
        __syncthreads();
        sm[tid] += v;
        __syncthreads();
    }
    if (tid < NB) part[tid] = (tid == 0) ? 0 : sm[tid - 1];  // exclusive block sums
    if (tid == 0) offsets[NN] = EE;
}

__global__ void scanchunk_kernel(const int* __restrict__ deg, const int* __restrict__ part,
                                 int* __restrict__ offsets, float* __restrict__ inv_cnt) {
    __shared__ int sm[256];
    int tid = threadIdx.x;
    int base = blockIdx.x * CH + tid * 4;
    int d0 = 0, d1 = 0, d2 = 0, d3 = 0;
    if (base + 0 < NN) d0 = deg[base + 0];
    if (base + 1 < NN) d1 = deg[base + 1];
    if (base + 2 < NN) d2 = deg[base + 2];
    if (base + 3 < NN) d3 = deg[base + 3];
    sm[tid] = d0 + d1 + d2 + d3;
    __syncthreads();
    for (int off = 1; off < 256; off <<= 1) {
        int v = (tid >= off) ? sm[tid - off] : 0;
        __syncthreads();
        sm[tid] += v;
        __syncthreads();
    }
    int carry = part[blockIdx.x] + ((tid == 0) ? 0 : sm[tid - 1]);
    int p0 = carry;
    int p1 = p0 + d0;
    int p2 = p1 + d1;
    int p3 = p2 + d2;
    if (base + 0 < NN) { offsets[base + 0] = p0; inv_cnt[base + 0] = 1.0f / (1.0f + (float)d0); }
    if (base + 1 < NN) { offsets[base + 1] = p1; inv_cnt[base + 1] = 1.0f / (1.0f + (float)d1); }
    if (base + 2 < NN) { offsets[base + 2] = p2; inv_cnt[base + 2] = 1.0f / (1.0f + (float)d2); }
    if (base + 3 < NN) { offsets[base + 3] = p3; inv_cnt[base + 3] = 1.0f / (1.0f + (float)d3); }
}

__global__ void place_kernel(const int* __restrict__ ei, int* __restrict__ cursor,
                             int* __restrict__ col) {
    int e = blockIdx.x * blockDim.x + threadIdx.x;
    if (e < EE) {
        int s = ei[e];            // src
        int d = ei[EE + e];       // dst
        int p = atomicAdd(&cursor[d], 1);
        col[p] = s;
    }
}

// ---------- fp32 -> fp16 conversion of x ----------
__global__ void cvt_kernel(const float4* __restrict__ x, f16x4* __restrict__ x16) {
    int i = blockIdx.x * blockDim.x + threadIdx.x;   // over N*T/4
    float4 v = x[i];
    f16x4 o;
    o.x = (f16)v.x; o.y = (f16)v.y; o.z = (f16)v.z; o.w = (f16)v.w;
    x16[i] = o;
}

// ---------- fused layer: y = relu(conv_nobias(gather(xin)) * inv_cnt + b) ----------
// One wave (64 lanes) per node; each lane owns t = {2*lane, 2*lane+1}.
// Gather sums fp16 rows (256B each) in fp32; conv K=9 done via wave shuffles.
__global__ void fused_layer_kernel(const f16x2* __restrict__ xin,   // [N*64] as half2
                                   const int* __restrict__ offsets,
                                   const int* __restrict__ col,
                                   const float* __restrict__ inv_cnt,
                                   const float* __restrict__ w9,
                                   const float* __restrict__ bptr,
                                   f16x2* __restrict__ yout) {
    int tid = threadIdx.x;
    int lane = tid & 63;
    int node = blockIdx.x * 4 + (tid >> 6);

    // self loop row
    f16x2 sv = xin[node * 64 + lane];
    float ax = (float)sv.x;
    float ay = (float)sv.y;

    int lo = offsets[node], hi = offsets[node + 1];
    int cnt = hi - lo;
    // lane-parallel col prefetch (one coalesced load covers deg<=64; tail loop for more)
    int my_col = (lane < cnt) ? col[lo + lane] : 0;
    int jn = cnt < 64 ? cnt : 64;
    int j = 0;
    for (; j + 3 < jn; j += 4) {
        int c0 = __shfl(my_col, j);
        int c1 = __shfl(my_col, j + 1);
        int c2 = __shfl(my_col, j + 2);
        int c3 = __shfl(my_col, j + 3);
        f16x2 v0 = xin[c0 * 64 + lane];
        f16x2 v1 = xin[c1 * 64 + lane];
        f16x2 v2 = xin[c2 * 64 + lane];
        f16x2 v3 = xin[c3 * 64 + lane];
        ax += (float)v0.x + (float)v1.x + (float)v2.x + (float)v3.x;
        ay += (float)v0.y + (float)v1.y + (float)v2.y + (float)v3.y;
    }
    for (; j < jn; j++) {
        int c = __shfl(my_col, j);
        f16x2 v = xin[c * 64 + lane];
        ax += (float)v.x;
        ay += (float)v.y;
    }
    for (int k = 64; k < cnt; k++) {      // rare: degree > 64
        int c = col[lo + k];
        f16x2 v = xin[c * 64 + lane];
        ax += (float)v.x;
        ay += (float)v.y;
    }

    // in-register conv K=9 via shuffles: lane needs t-4..t+5 => lanes L-2..L+2
    float u1x = __shfl_up(ax, 1), u1y = __shfl_up(ay, 1);
    float u2x = __shfl_up(ax, 2), u2y = __shfl_up(ay, 2);
    float d1x = __shfl_down(ax, 1), d1y = __shfl_down(ay, 1);
    float d2x = __shfl_down(ax, 2), d2y = __shfl_down(ay, 2);
    if (lane < 1) { u1x = 0.0f; u1y = 0.0f; }
    if (lane < 2) { u2x = 0.0f; u2y = 0.0f; }
    if (lane > 62) { d1x = 0.0f; d1y = 0.0f; }
    if (lane > 61) { d2x = 0.0f; d2y = 0.0f; }

    float w0 = w9[0], w1 = w9[1], w2 = w9[2], w3 = w9[3], w4 = w9[4];
    float w5 = w9[5], w6 = w9[6], w7 = w9[7], w8 = w9[8];
    // t = 2L:   window [u2x u2y u1x u1y ax ay d1x d1y d2x]
    float s0 = u2x * w0 + u2y * w1 + u1x * w2 + u1y * w3 + ax * w4
             + ay * w5 + d1x * w6 + d1y * w7 + d2x * w8;
    // t = 2L+1: window [u2y u1x u1y ax ay d1x d1y d2x d2y]
    float s1 = u2y * w0 + u1x * w1 + u1y * w2 + ax * w3 + ay * w4
             + d1x * w5 + d1y * w6 + d2x * w7 + d2y * w8;

    float ic = inv_cnt[node];
    float b = bptr[0];
    s0 = fmaxf(s0 * ic + b, 0.0f);
    s1 = fmaxf(s1 * ic + b, 0.0f);
    f16x2 o;
    o.x = (f16)s0;
    o.y = (f16)s1;
    yout[node * 64 + lane] = o;
}

// out[r,c] = b[c] + sum_n y3flat[r*NN + n] * Wout[c*NN + n]   (flat reinterpret view)
__global__ void out_kernel(const f16* __restrict__ y3, const float* __restrict__ Wout,
                           const float* __restrict__ bout, float* __restrict__ out) {
    int t = blockIdx.x;
    int sp = blockIdx.y;
    int tid = threadIdx.x;
    const int per = NN / NSPLIT;   // 12500
    int lo = sp * per;
    int hi = lo + per;
    float a0 = 0.0f, a1 = 0.0f, a2 = 0.0f;
    for (int n = lo + tid * 2; n < hi; n += 512) {
        f16x2 v2 = *(const f16x2*)(y3 + (size_t)t * NN + n);
        float vx = (float)v2.x, vy = (float)v2.y;
        float2 wA = *(const float2*)(Wout + n);
        float2 wB = *(const float2*)(Wout + NN + n);
        float2 wC = *(const float2*)(Wout + 2 * NN + n);
        a0 += vx * wA.x + vy * wA.y;
        a1 += vx * wB.x + vy * wB.y;
        a2 += vx * wC.x + vy * wC.y;
    }
    for (int o = 32; o > 0; o >>= 1) {
        a0 += __shfl_down(a0, o);
        a1 += __shfl_down(a1, o);
        a2 += __shfl_down(a2, o);
    }
    __shared__ float red[4][3];
    int wave = tid >> 6;
    if ((tid & 63) == 0) {
        red[wave][0] = a0;
        red[wave][1] = a1;
        red[wave][2] = a2;
    }
    __syncthreads();
    if (tid == 0) {
        float r0 = red[0][0] + red[1][0] + red[2][0] + red[3][0];
        float r1 = red[0][1] + red[1][1] + red[2][1] + red[3][1];
        float r2 = red[0][2] + red[1][2] + red[2][2] + red[3][2];
        if (sp == 0) {
            r0 += bout[0];
            r1 += bout[1];
            r2 += bout[2];
        }
        atomicAdd(&out[t * 3 + 0], r0);
        atomicAdd(&out[t * 3 + 1], r1);
        atomicAdd(&out[t * 3 + 2], r2);
    }
}

extern "C" void kernel_launch(void* const* d_in, const int* in_sizes, int n_in,
                              void* d_out, int out_size, void* d_ws, size_t ws_size,
                              hipStream_t stream) {
    const float* x    = (const float*)d_in[0];   // [N,T]
    const int*   ei   = (const int*)d_in[1];     // [2,E]
    const float* cw   = (const float*)d_in[2];   // [L,1,1,K]
    const float* cb   = (const float*)d_in[3];   // [L,1]
    const float* Wout = (const float*)d_in[4];   // [3,N]
    const float* bout = (const float*)d_in[5];   // [3]
    float* out = (float*)d_out;                  // [T,3]

    char* ws = (char*)d_ws;
    size_t off = 0;
    auto alloc = [&](size_t bytes) -> void* {
        void* p = ws + off;
        off += (bytes + 255) & ~(size_t)255;
        return p;
    };
    f16*   x16     = (f16*)alloc((size_t)NN * TT * 2);
    f16*   yA      = (f16*)alloc((size_t)NN * TT * 2);
    f16*   yB      = (f16*)alloc((size_t)NN * TT * 2);
    int*   deg     = (int*)alloc((size_t)NN * 4);
    int*   offsets = (int*)alloc((size_t)(NN + 1) * 4);
    int*   cursor  = (int*)alloc((size_t)NN * 4);
    int*   col     = (int*)alloc((size_t)EE * 4);
    float* inv_cnt = (float*)alloc((size_t)NN * 4);
    int*   part    = (int*)alloc((size_t)NB * 4);

    // CSR build (per call — ws is re-poisoned before every launch)
    hipMemsetAsync(deg, 0, (size_t)NN * 4, stream);
    hist_kernel<<<(EE + 255) / 256, 256, 0, stream>>>(ei, deg);
    partial_kernel<<<NB, 256, 0, stream>>>(deg, part);
    scanpart_kernel<<<1, 128, 0, stream>>>(part, offsets);
    scanchunk_kernel<<<NB, 256, 0, stream>>>(deg, part, offsets, inv_cnt);
    hipMemcpyAsync(cursor, offsets, (size_t)NN * 4, hipMemcpyDeviceToDevice, stream);
    place_kernel<<<(EE + 255) / 256, 256, 0, stream>>>(ei, cursor, col);

    // x -> fp16
    cvt_kernel<<<(NN * TT / 4 + 255) / 256, 256, 0, stream>>>((const float4*)x, (f16x4*)x16);

    // 3 fused layers (conv commuted past gather; bias/mean folded exactly)
    fused_layer_kernel<<<NN / 4, 256, 0, stream>>>((const f16x2*)x16, offsets, col, inv_cnt,
                                                   cw + 0 * KK, cb + 0, (f16x2*)yA);
    fused_layer_kernel<<<NN / 4, 256, 0, stream>>>((const f16x2*)yA, offsets, col, inv_cnt,
                                                   cw + 1 * KK, cb + 1, (f16x2*)yB);
    fused_layer_kernel<<<NN / 4, 256, 0, stream>>>((const f16x2*)yB, offsets, col, inv_cnt,
                                                   cw + 2 * KK, cb + 2, (f16x2*)yA);

    // output head (y3 = yA already has relu/mean applied)
    hipMemsetAsync(out, 0, (size_t)TT * 3 * 4, stream);
    out_kernel<<<dim3(TT, NSPLIT), 256, 0, stream>>>(yA, Wout, bout, out);
}

// Round 3
// 358.494 us; speedup vs baseline: 2.1243x; 1.4112x over previous
//
#include <hip/hip_runtime.h>

// Problem constants (match reference)
#define NN 100000
#define TT 128
#define EE 1600000
#define KK 9
#define PADK 4
#define NSPLIT 8                  // n-splits for output matmul

// Binned CSR build
#define BSH 9                     // 512 nodes per bucket
#define BMASK 511
#define NBUCK 196                 // ceil(100000/512)
#define BCAP 10240                // avg 8163/bucket, sigma~90 -> 23 sigma headroom

typedef _Float16 f16;
typedef __attribute__((ext_vector_type(2))) _Float16 f16x2;
typedef __attribute__((ext_vector_type(4))) _Float16 f16x4;

// ---------- CSR build, phase 1: bin edges by dst range ----------
// Packed edge: (dlocal << 20) | src   (src < 2^17, dlocal < 2^9)
__global__ void bin_kernel(const int* __restrict__ ei, int* __restrict__ gcursor,
                           unsigned int* __restrict__ binned) {
    __shared__ int hist[NBUCK];
    __shared__ int gbase[NBUCK];
    int tid = threadIdx.x;
    for (int i = tid; i < NBUCK; i += 256) hist[i] = 0;
    __syncthreads();
    int base = blockIdx.x * 2048;
    unsigned int val[8];
    int bkt[8];
    int rank[8];
#pragma unroll
    for (int k = 0; k < 8; k++) {
        int e = base + k * 256 + tid;
        bkt[k] = -1;
        if (e < EE) {
            int s = ei[e];            // src
            int d = ei[EE + e];       // dst
            bkt[k] = d >> BSH;
            val[k] = ((unsigned int)(d & BMASK) << 20) | (unsigned int)s;
            rank[k] = atomicAdd(&hist[bkt[k]], 1);
        }
    }
    __syncthreads();
    for (int i = tid; i < NBUCK; i += 256)
        gbase[i] = hist[i] ? atomicAdd(&gcursor[i], hist[i]) : 0;
    __syncthreads();
#pragma unroll
    for (int k = 0; k < 8; k++) {
        if (bkt[k] >= 0)
            binned[(size_t)bkt[k] * BCAP + gbase[bkt[k]] + rank[k]] = val[k];
    }
}

// ---------- CSR build, phase 2a: scan bucket counts -> bucket bases ----------
__global__ void scanpart_kernel(const int* __restrict__ gcursor, int* __restrict__ part,
                                int* __restrict__ offsets) {
    __shared__ int sm[256];
    int tid = threadIdx.x;
    sm[tid] = (tid < NBUCK) ? gcursor[tid] : 0;
    __syncthreads();
    for (int off = 1; off < 256; off <<= 1) {
        int v = (tid >= off) ? sm[tid - off] : 0;
        __syncthreads();
        sm[tid] += v;
        __syncthreads();
    }
    if (tid < NBUCK) part[tid] = (tid == 0) ? 0 : sm[tid - 1];
    if (tid == 0) offsets[NN] = EE;
}

// ---------- CSR build, phase 2b: per-bucket hist + scan + offsets/inv_cnt + place ----------
__global__ void bucket_csr_kernel(const unsigned int* __restrict__ binned,
                                  const int* __restrict__ gcursor,
                                  const int* __restrict__ part,
                                  int* __restrict__ offsets,
                                  float* __restrict__ inv_cnt,
                                  int* __restrict__ col) {
    __shared__ int hist[512];
    __shared__ int cur[512];
    __shared__ int sm[256];
    int b = blockIdx.x;
    int tid = threadIdx.x;
    int cnt = gcursor[b];
    const unsigned int* ePtr = binned + (size_t)b * BCAP;
    hist[tid] = 0;
    hist[tid + 256] = 0;
    __syncthreads();
    for (int j = tid; j < cnt; j += 256)
        atomicAdd(&hist[ePtr[j] >> 20], 1);
    __syncthreads();
    // exclusive scan of 512 degree counts (thread t owns entries 2t, 2t+1)
    int d0 = hist[2 * tid], d1 = hist[2 * tid + 1];
    sm[tid] = d0 + d1;
    __syncthreads();
    for (int off = 1; off < 256; off <<= 1) {
        int v = (tid >= off) ? sm[tid - off] : 0;
        __syncthreads();
        sm[tid] += v;
        __syncthreads();
    }
    int basep = part[b] + ((tid == 0) ? 0 : sm[tid - 1]);
    int node0 = (b << BSH) + 2 * tid;
    int p0 = basep;
    int p1 = basep + d0;
    if (node0 < NN) {
        offsets[node0] = p0;
        inv_cnt[node0] = 1.0f / (1.0f + (float)d0);
        cur[2 * tid] = p0;
    }
    if (node0 + 1 < NN) {
        offsets[node0 + 1] = p1;
        inv_cnt[node0 + 1] = 1.0f / (1.0f + (float)d1);
        cur[2 * tid + 1] = p1;
    }
    __syncthreads();
    // place: all writes land in this bucket's contiguous col window (~32 KB, L2-resident)
    for (int j = tid; j < cnt; j += 256) {
        unsigned int v = ePtr[j];
        int pos = atomicAdd(&cur[v >> 20], 1);
        col[pos] = (int)(v & 0xFFFFF);
    }
}

// ---------- fp32 -> fp16 conversion of x ----------
__global__ void cvt_kernel(const float4* __restrict__ x, f16x4* __restrict__ x16) {
    int i = blockIdx.x * blockDim.x + threadIdx.x;   // over N*T/4
    float4 v = x[i];
    f16x4 o;
    o.x = (f16)v.x; o.y = (f16)v.y; o.z = (f16)v.z; o.w = (f16)v.w;
    x16[i] = o;
}

// ---------- fused layer: y = relu(conv_nobias(gather(xin)) * inv_cnt + b) ----------
// One wave (64 lanes) per node; each lane owns t = {2*lane, 2*lane+1}.
__global__ void fused_layer_kernel(const f16x2* __restrict__ xin,   // [N*64] as half2
                                   const int* __restrict__ offsets,
                                   const int* __restrict__ col,
                                   const float* __restrict__ inv_cnt,
                                   const float* __restrict__ w9,
                                   const float* __restrict__ bptr,
                                   f16x2* __restrict__ yout) {
    int tid = threadIdx.x;
    int lane = tid & 63;
    int node = blockIdx.x * 4 + (tid >> 6);

    // self loop row
    f16x2 sv = xin[node * 64 + lane];
    float ax = (float)sv.x;
    float ay = (float)sv.y;

    int lo = offsets[node], hi = offsets[node + 1];
    int cnt = hi - lo;
    // lane-parallel col prefetch (one coalesced load covers deg<=64; tail loop for more)
    int my_col = (lane < cnt) ? col[lo + lane] : 0;
    int jn = cnt < 64 ? cnt : 64;
    int j = 0;
    for (; j + 3 < jn; j += 4) {
        int c0 = __shfl(my_col, j);
        int c1 = __shfl(my_col, j + 1);
        int c2 = __shfl(my_col, j + 2);
        int c3 = __shfl(my_col, j + 3);
        f16x2 v0 = xin[c0 * 64 + lane];
        f16x2 v1 = xin[c1 * 64 + lane];
        f16x2 v2 = xin[c2 * 64 + lane];
        f16x2 v3 = xin[c3 * 64 + lane];
        ax += (float)v0.x + (float)v1.x + (float)v2.x + (float)v3.x;
        ay += (float)v0.y + (float)v1.y + (float)v2.y + (float)v3.y;
    }
    for (; j < jn; j++) {
        int c = __shfl(my_col, j);
        f16x2 v = xin[c * 64 + lane];
        ax += (float)v.x;
        ay += (float)v.y;
    }
    for (int k = 64; k < cnt; k++) {      // rare: degree > 64
        int c = col[lo + k];
        f16x2 v = xin[c * 64 + lane];
        ax += (float)v.x;
        ay += (float)v.y;
    }

    // in-register conv K=9 via shuffles: lane needs t-4..t+5 => lanes L-2..L+2
    float u1x = __shfl_up(ax, 1), u1y = __shfl_up(ay, 1);
    float u2x = __shfl_up(ax, 2), u2y = __shfl_up(ay, 2);
    float d1x = __shfl_down(ax, 1), d1y = __shfl_down(ay, 1);
    float d2x = __shfl_down(ax, 2), d2y = __shfl_down(ay, 2);
    if (lane < 1) { u1x = 0.0f; u1y = 0.0f; }
    if (lane < 2) { u2x = 0.0f; u2y = 0.0f; }
    if (lane > 62) { d1x = 0.0f; d1y = 0.0f; }
    if (lane > 61) { d2x = 0.0f; d2y = 0.0f; }

    float w0 = w9[0], w1 = w9[1], w2 = w9[2], w3 = w9[3], w4 = w9[4];
    float w5 = w9[5], w6 = w9[6], w7 = w9[7], w8 = w9[8];
    // t = 2L:   window [u2x u2y u1x u1y ax ay d1x d1y d2x]
    float s0 = u2x * w0 + u2y * w1 + u1x * w2 + u1y * w3 + ax * w4
             + ay * w5 + d1x * w6 + d1y * w7 + d2x * w8;
    // t = 2L+1: window [u2y u1x u1y ax ay d1x d1y d2x d2y]
    float s1 = u2y * w0 + u1x * w1 + u1y * w2 + ax * w3 + ay * w4
             + d1x * w5 + d1y * w6 + d2x * w7 + d2y * w8;

    float ic = inv_cnt[node];
    float b = bptr[0];
    s0 = fmaxf(s0 * ic + b, 0.0f);
    s1 = fmaxf(s1 * ic + b, 0.0f);
    f16x2 o;
    o.x = (f16)s0;
    o.y = (f16)s1;
    yout[node * 64 + lane] = o;
}

// out[r,c] = b[c] + sum_n y3flat[r*NN + n] * Wout[c*NN + n]   (flat reinterpret view)
__global__ void out_kernel(const f16* __restrict__ y3, const float* __restrict__ Wout,
                           const float* __restrict__ bout, float* __restrict__ out) {
    int t = blockIdx.x;
    int sp = blockIdx.y;
    int tid = threadIdx.x;
    const int per = NN / NSPLIT;   // 12500
    int lo = sp * per;
    int hi = lo + per;
    float a0 = 0.0f, a1 = 0.0f, a2 = 0.0f;
    for (int n = lo + tid * 2; n < hi; n += 512) {
        f16x2 v2 = *(const f16x2*)(y3 + (size_t)t * NN + n);
        float vx = (float)v2.x, vy = (float)v2.y;
        float2 wA = *(const float2*)(Wout + n);
        float2 wB = *(const float2*)(Wout + NN + n);
        float2 wC = *(const float2*)(Wout + 2 * NN + n);
        a0 += vx * wA.x + vy * wA.y;
        a1 += vx * wB.x + vy * wB.y;
        a2 += vx * wC.x + vy * wC.y;
    }
    for (int o = 32; o > 0; o >>= 1) {
        a0 += __shfl_down(a0, o);
        a1 += __shfl_down(a1, o);
        a2 += __shfl_down(a2, o);
    }
    __shared__ float red[4][3];
    int wave = tid >> 6;
    if ((tid & 63) == 0) {
        red[wave][0] = a0;
        red[wave][1] = a1;
        red[wave][2] = a2;
    }
    __syncthreads();
    if (tid == 0) {
        float r0 = red[0][0] + red[1][0] + red[2][0] + red[3][0];
        float r1 = red[0][1] + red[1][1] + red[2][1] + red[3][1];
        float r2 = red[0][2] + red[1][2] + red[2][2] + red[3][2];
        if (sp == 0) {
            r0 += bout[0];
            r1 += bout[1];
            r2 += bout[2];
        }
        atomicAdd(&out[t * 3 + 0], r0);
        atomicAdd(&out[t * 3 + 1], r1);
        atomicAdd(&out[t * 3 + 2], r2);
    }
}

extern "C" void kernel_launch(void* const* d_in, const int* in_sizes, int n_in,
                              void* d_out, int out_size, void* d_ws, size_t ws_size,
                              hipStream_t stream) {
    const float* x    = (const float*)d_in[0];   // [N,T]
    const int*   ei   = (const int*)d_in[1];     // [2,E]
    const float* cw   = (const float*)d_in[2];   // [L,1,1,K]
    const float* cb   = (const float*)d_in[3];   // [L,1]
    const float* Wout = (const float*)d_in[4];   // [3,N]
    const float* bout = (const float*)d_in[5];   // [3]
    float* out = (float*)d_out;                  // [T,3]

    char* ws = (char*)d_ws;
    size_t off = 0;
    auto alloc = [&](size_t bytes) -> void* {
        void* p = ws + off;
        off += (bytes + 255) & ~(size_t)255;
        return p;
    };
    f16*          x16     = (f16*)alloc((size_t)NN * TT * 2);
    f16*          yA      = (f16*)alloc((size_t)NN * TT * 2);
    f16*          yB      = (f16*)alloc((size_t)NN * TT * 2);
    unsigned int* binned  = (unsigned int*)alloc((size_t)NBUCK * BCAP * 4);
    int*          gcursor = (int*)alloc((size_t)NBUCK * 4);
    int*          part    = (int*)alloc((size_t)NBUCK * 4);
    int*          offsets = (int*)alloc((size_t)(NN + 1) * 4);
    float*        inv_cnt = (float*)alloc((size_t)NN * 4);
    int*          col     = (int*)alloc((size_t)EE * 4);

    // CSR build (per call — ws is re-poisoned before every launch)
    hipMemsetAsync(gcursor, 0, (size_t)NBUCK * 4, stream);
    bin_kernel<<<(EE + 2047) / 2048, 256, 0, stream>>>(ei, gcursor, binned);
    scanpart_kernel<<<1, 256, 0, stream>>>(gcursor, part, offsets);
    bucket_csr_kernel<<<NBUCK, 256, 0, stream>>>(binned, gcursor, part, offsets, inv_cnt, col);

    // x -> fp16
    cvt_kernel<<<(NN * TT / 4 + 255) / 256, 256, 0, stream>>>((const float4*)x, (f16x4*)x16);

    // 3 fused layers (conv commuted past gather; bias/mean folded exactly)
    fused_layer_kernel<<<NN / 4, 256, 0, stream>>>((const f16x2*)x16, offsets, col, inv_cnt,
                                                   cw + 0 * KK, cb + 0, (f16x2*)yA);
    fused_layer_kernel<<<NN / 4, 256, 0, stream>>>((const f16x2*)yA, offsets, col, inv_cnt,
                                                   cw + 1 * KK, cb + 1, (f16x2*)yB);
    fused_layer_kernel<<<NN / 4, 256, 0, stream>>>((const f16x2*)yB, offsets, col, inv_cnt,
                                                   cw + 2 * KK, cb + 2, (f16x2*)yA);

    // output head (y3 = yA already has relu/mean applied)
    hipMemsetAsync(out, 0, (size_t)TT * 3 * 4, stream);
    out_kernel<<<dim3(TT, NSPLIT), 256, 0, stream>>>(yA, Wout, bout, out);
}